// Round 1
// 2760.793 us; speedup vs baseline: 1.1763x; 1.1763x over previous
//
#include <hip/hip_runtime.h>
#include <stdint.h>

// S=64, B=64, C=H=E=512, V=32000, steps T=48
// Phase 1: ONE persistent kernel (96 WGs), 3 sub-phases/step on the critical path:
//   Group A (WG 0-31):  P0: gru0 -> h1 (bf16 packed) + split-K q-partials, then
//                       attention for b=wg
//   Group B (WG 32-63): gh1 in REGISTERS (off critical path), then P3:
//                       gi1 = catt@Wcomb^T + combine -> h2 (fp32 + bf16 packed)
//   Group C (WG 64-95): attention for b=32..63
// Sync: scattered per-WG token slots, NEIGHBOR-ONLY waits (8/16 slots = true deps),
// s_sleep(2) polling. 3 handoffs/step (barD -> barA -> barC) instead of 4.

using bf16x8 = __attribute__((ext_vector_type(8))) short;
using f32x4  = __attribute__((ext_vector_type(4))) float;
using s16x4  = __attribute__((ext_vector_type(4))) short;
typedef unsigned long long u64;
typedef unsigned int u32;

#define DI __device__ __forceinline__

DI short f2bf(float x){
  union { float f; uint32_t u; } v; v.f = x;
  uint32_t r = (v.u + 0x7FFFu + ((v.u >> 16) & 1u)) >> 16;
  return (short)r;
}
DI float bf2f(short s){
  union { uint32_t u; float f; } v; v.u = ((uint32_t)(unsigned short)s) << 16; return v.f;
}
DI float sigm(float x){ return __fdividef(1.f, 1.f + __expf(-x)); }
DI float ftanh(float x){ return 1.f - __fdividef(2.f, __expf(2.f*x) + 1.f); }
DI float wsum(float v){
  #pragma unroll
  for (int m = 32; m > 0; m >>= 1) v += __shfl_xor(v, m, 64);
  return v;
}
DI f32x4 mfma16(bf16x8 a, bf16x8 b, f32x4 c){
  return __builtin_amdgcn_mfma_f32_16x16x32_bf16(a, b, c, 0, 0, 0);
}

// AGENT-scope atomics (reach/observe coherence point; no local stale copies)
DI u32  ald32(const u32* p){ return __hip_atomic_load(p, __ATOMIC_RELAXED, __HIP_MEMORY_SCOPE_AGENT); }
DI void ast32(u32* p, u32 v){ __hip_atomic_store(p, v, __ATOMIC_RELAXED, __HIP_MEMORY_SCOPE_AGENT); }
DI u64  ald64(const u64* p){ return __hip_atomic_load(p, __ATOMIC_RELAXED, __HIP_MEMORY_SCOPE_AGENT); }
DI void ast64(u64* p, u64 v){ __hip_atomic_store(p, v, __ATOMIC_RELAXED, __HIP_MEMORY_SCOPE_AGENT); }
DI float aldf(const float* p){ return __hip_atomic_load(p, __ATOMIC_RELAXED, __HIP_MEMORY_SCOPE_AGENT); }
DI void astf(float* p, float v){ __hip_atomic_store(p, v, __ATOMIC_RELAXED, __HIP_MEMORY_SCOPE_AGENT); }

// plain bf16 weight fragment (row-major [N][512])
DI bf16x8 ldb(const short* __restrict__ W, int n0, int k0, int lane){
  return *(const bf16x8*)(W + (size_t)(n0 + (lane & 15)) * 512 + k0 + ((lane >> 4) << 3));
}

#define SLOT 64   // dwords per token slot (256 B padding)

// signal: call AFTER __syncthreads() (compiler drains vmcnt before s_barrier)
DI void sig(u32* arr, int slot, u32 tok){
  if (threadIdx.x == 0){
    __builtin_amdgcn_s_waitcnt(0);
    ast32(arr + slot * SLOT, tok);
  }
}
// wait: lane i (<cnt) polls slot base+i; all-ballot; then block barrier
DI void waitslots(const u32* arr, int base, int cnt, u32 tok){
  if (threadIdx.x < 64){
    for (;;){
      u32 v = (threadIdx.x < cnt) ? ald32(arr + (base + threadIdx.x) * SLOT) : tok;
      if (__all((int)(v - tok) >= 0)) break;
      __builtin_amdgcn_s_sleep(2);
    }
  }
  __syncthreads();
}

// ---------------- elementwise / prep kernels ----------------

struct CvtJobs { const float* src[8]; short* dst[8]; int cum4[9]; };

__global__ __launch_bounds__(256) void k_cvt_multi(CvtJobs jb, int total4){
  int i = blockIdx.x * 256 + threadIdx.x;
  if (i >= total4) return;
  int j = 0;
  #pragma unroll
  for (int k = 0; k < 8; ++k) if (i >= jb.cum4[k + 1]) j = k + 1;
  int off = i - jb.cum4[j];
  float4 v = ((const float4*)jb.src[j])[off];
  s16x4 o; o[0] = f2bf(v.x); o[1] = f2bf(v.y); o[2] = f2bf(v.z); o[3] = f2bf(v.w);
  ((s16x4*)jb.dst[j])[off] = o;
}

__global__ __launch_bounds__(256) void k_tc(const float* __restrict__ W, short* __restrict__ WT){
  int i = blockIdx.x * 256 + threadIdx.x;
  int c = i >> 9, h = i & 511;
  WT[i] = f2bf(W[h * 512 + c]);
}

__global__ __launch_bounds__(256) void k_zero(float* __restrict__ p, int n){
  int i = blockIdx.x * 256 + threadIdx.x;
  if (i < n) p[i] = 0.f;
}

__global__ __launch_bounds__(256) void k_meanmix(const float* __restrict__ ctx, const float* __restrict__ mask,
                                                 const float* __restrict__ txt, float* __restrict__ mixed){
  int i = blockIdx.x * 256 + threadIdx.x;
  int b = i >> 9, c = i & 511;
  float s = 0.f;
  for (int t = 0; t < 64; ++t) s += ctx[(size_t)(t * 64 + b) * 512 + c];
  float dn = 0.f;
  for (int t = 0; t < 64; ++t) dn += mask[t * 64 + b];
  mixed[i] = 0.5f * (s / dn) + 0.5f * txt[i];
}

// pack h0 fp32 -> bf16 packed
__global__ __launch_bounds__(256) void k_pack_h0(const float* __restrict__ h0, u32* __restrict__ hbf){
  int i = blockIdx.x * 256 + threadIdx.x;   // 0..16383
  u32 lo = (u32)(unsigned short)f2bf(h0[2 * i]);
  u32 hi = (u32)(unsigned short)f2bf(h0[2 * i + 1]);
  hbf[i] = lo | (hi << 16);
}

// ---------------- generic wave-tile GEMMs (K = 512, fp32 A) ----------------

DI bf16x8 load_a32(const float* __restrict__ A, int ld, int m0, int k0, int lane){
  const float* p = A + (size_t)(m0 + (lane & 15)) * ld + k0 + ((lane >> 4) << 3);
  bf16x8 f;
  #pragma unroll
  for (int j = 0; j < 8; ++j) f[j] = f2bf(p[j]);
  return f;
}

__global__ __launch_bounds__(256) void k_gemm_bt(const float* __restrict__ A, const short* __restrict__ W,
                                                 float* __restrict__ C, int N, int act){
  int wg = blockIdx.x * 4 + (threadIdx.x >> 6);
  int lane = threadIdx.x & 63;
  int ntiles = N >> 4;
  int mt = wg / ntiles, nt = wg - mt * ntiles;
  int m0 = mt << 4, n0 = nt << 4;
  f32x4 acc = {0.f, 0.f, 0.f, 0.f};
  for (int k = 0; k < 512; k += 32)
    acc = mfma16(load_a32(A, 512, m0, k, lane), ldb(W, n0, k, lane), acc);
  int col = n0 + (lane & 15);
  int r0 = m0 + ((lane >> 4) << 2);
  #pragma unroll
  for (int r = 0; r < 4; ++r){
    float v = acc[r];
    if (act) v = ftanh(v);
    C[(size_t)(r0 + r) * N + col] = v;
  }
}

__global__ __launch_bounds__(256) void k_gemm_bt_obf(const float* __restrict__ A, const short* __restrict__ W,
                                                     short* __restrict__ C, int N){
  int wg = blockIdx.x * 4 + (threadIdx.x >> 6);
  int lane = threadIdx.x & 63;
  int ntiles = N >> 4;
  int mt = wg / ntiles, nt = wg - mt * ntiles;
  int m0 = mt << 4, n0 = nt << 4;
  f32x4 acc = {0.f, 0.f, 0.f, 0.f};
  for (int k = 0; k < 512; k += 32)
    acc = mfma16(load_a32(A, 512, m0, k, lane), ldb(W, n0, k, lane), acc);
  int col = n0 + (lane & 15);
  int r0 = m0 + ((lane >> 4) << 2);
  #pragma unroll
  for (int r = 0; r < 4; ++r)
    C[(size_t)(r0 + r) * N + col] = f2bf(acc[r]);
}

__global__ __launch_bounds__(256) void k_gi0(const int* __restrict__ y, const float* __restrict__ emb,
                                             const short* __restrict__ W, const float* __restrict__ bias,
                                             float* __restrict__ C){
  int wg = blockIdx.x * 4 + (threadIdx.x >> 6);
  int lane = threadIdx.x & 63;
  int mt = wg / 96, nt = wg - mt * 96;
  int m0 = mt << 4, n0 = nt << 4;
  int yr = y[m0 + (lane & 15)];
  const float* arow = emb + (size_t)yr * 512;
  f32x4 acc = {0.f, 0.f, 0.f, 0.f};
  for (int k = 0; k < 512; k += 32){
    const float* p = arow + k + ((lane >> 4) << 3);
    bf16x8 a;
    #pragma unroll
    for (int j = 0; j < 8; ++j) a[j] = f2bf(p[j]);
    acc = mfma16(a, ldb(W, n0, k, lane), acc);
  }
  int col = n0 + (lane & 15);
  int r0 = m0 + ((lane >> 4) << 2);
  #pragma unroll
  for (int r = 0; r < 4; ++r)
    C[(size_t)(r0 + r) * 1536 + col] = acc[r] + bias[col];
}

// ---------------- persistent recurrence kernel ----------------

struct RB {
  const float* gi0;        // [48][64][1536] fp32 (incl b_ih0)
  const short* Whh0; const float* bhh0;
  const short* Whid2ctx;   // bf16 [512][512]
  const short* Whh1; const float* bhh1;
  const short* Wcomb; const float* bih1;
  const short* ctx_proj;   // bf16 [s*64+b][512]
  const float* ctx;        // fp32 [s*64+b][512]
  const float* mask;       // [64][64] (s,b)
  const float* wmlp;       // [512]
  unsigned short* h_bf;    // [64][512] bf16 (recurrent state)
  unsigned short* h1_bf;   // [64][512] bf16
  unsigned short* catt_bf; // [64][512] bf16
  float* qpart;            // [8 cg][64 b][512] fp32 split-K q partials
  float* h2;               // [48][64][512] fp32 (plain, for phase 2)
  u32* barA; u32* barC; u32* barD;  // token slots, stride SLOT
};

__global__ __launch_bounds__(256, 1) void k_recur(RB a){
  __shared__ unsigned short sH[16 * 520];   // burst tile (rows x 512, pad 8)
  __shared__ float sOut[16 * 64];
  __shared__ float qs[512];
  __shared__ float wm[512];
  __shared__ float sc[64], al[64];
  const int wg = blockIdx.x, tid = threadIdx.x;
  const int wv = tid >> 6, lane = tid & 63;

  wm[tid] = a.wmlp[tid]; wm[tid + 256] = a.wmlp[tid + 256];
  __syncthreads();

  // burst 16 rows x 512 bf16 into sH
  auto burst16 = [&](const unsigned short* src, int row0){
    #pragma unroll
    for (int i = 0; i < 8; ++i){
      int idx = tid + i * 256;              // 0..2047
      int r = idx >> 7, c4 = idx & 127;     // 128 b64-chunks per row
      u64 v = ald64((const u64*)(src + (size_t)(row0 + r) * 512) + c4);
      *(u64*)(sH + r * 520 + c4 * 4) = v;
    }
    __syncthreads();
  };
  auto afrag = [&](int k0) -> bf16x8 {
    return *(const bf16x8*)(sH + (lane & 15) * 520 + k0 + ((lane >> 4) << 3));
  };
  auto packstore = [&](unsigned short* dst, int mrow0, int jbase){
    int r = tid >> 4, ch = tid & 15;
    float4 v = *(const float4*)&sOut[r * 64 + ch * 4];
    u64 pk = (u64)(unsigned short)f2bf(v.x)
           | ((u64)(unsigned short)f2bf(v.y) << 16)
           | ((u64)(unsigned short)f2bf(v.z) << 32)
           | ((u64)(unsigned short)f2bf(v.w) << 48);
    ast64((u64*)(dst + (size_t)(mrow0 + r) * 512 + jbase + ch * 4), pk);
  };
  // attention for batch element b (sums the 8 split-K q partials first)
  auto attention = [&](int b){
    float q0 = 0.f, q1 = 0.f;
    #pragma unroll
    for (int cgi = 0; cgi < 8; ++cgi){
      u64 v = ald64((const u64*)(a.qpart + (size_t)(cgi * 64 + b) * 512) + tid);
      union { u64 u; float f[2]; } cv; cv.u = v;
      q0 += cv.f[0]; q1 += cv.f[1];
    }
    qs[2 * tid] = q0; qs[2 * tid + 1] = q1;
    __syncthreads();
    for (int i = 0; i < 16; ++i){
      int s = (wv << 4) + i;
      const short* cp = a.ctx_proj + (size_t)((s << 6) + b) * 512 + lane * 8;
      bf16x8 c8 = *(const bf16x8*)cp;
      float p = 0.f;
      #pragma unroll
      for (int j = 0; j < 8; ++j){
        int m = lane * 8 + j;
        p += ftanh(bf2f(c8[j]) + qs[m]) * wm[m];
      }
      p = wsum(p);
      if (lane == 0) sc[s] = p;
    }
    __syncthreads();
    if (tid < 64){
      float mk = a.mask[(tid << 6) + b];
      float v = (mk > 0.f) ? sc[tid] : -100000000.0f;
      float mx = v;
      #pragma unroll
      for (int m = 32; m > 0; m >>= 1) mx = fmaxf(mx, __shfl_xor(mx, m, 64));
      float e = __expf(v - mx);
      float se = e;
      #pragma unroll
      for (int m = 32; m > 0; m >>= 1) se += __shfl_xor(se, m, 64);
      al[tid] = e / se;
    }
    __syncthreads();
    float s0 = 0.f, s1 = 0.f;
    int c0 = tid * 2;
    for (int s = 0; s < 64; ++s){
      float2 cv = *(const float2*)(a.ctx + (size_t)((s << 6) + b) * 512 + c0);
      s0 += al[s] * cv.x; s1 += al[s] * cv.y;
    }
    u32 pk = (u32)(unsigned short)f2bf(s0) | ((u32)(unsigned short)f2bf(s1) << 16);
    ast32((u32*)a.catt_bf + (size_t)b * 256 + tid, pk);
  };

  if (wg < 32){
    // ---- Group A: P0 (gru0 + split-K q partials), then attention b=wg ----
    const int rg = wg >> 3, cg = wg & 7;
    const int mrow0 = rg << 4, jbase = cg << 6;
    const int j0 = jbase + (wv << 4);
    const int col = j0 + (lane & 15), lcol = col - jbase;
    const int lr0 = (lane >> 4) << 2;
    const int batt = wg;
    const int abase = (batt >> 4) << 3;   // barA slots of row-group producing q for batt
    #pragma unroll 1
    for (int t = 0; t < 48; ++t){
      const u32 tok = t + 1;
      // h(t-1) ready: only the 8 same-row-group B WGs matter (t=0 trivially passes)
      waitslots(a.barD, rg << 3, 8, (u32)t);
      burst16(a.h_bf, mrow0);
      // prefetch gi0 operands (cold HBM stream) so they hide under the GEMM
      const float* gi = a.gi0 + (size_t)t * 98304;
      float giv0[4], giv1[4], giv2[4];
      #pragma unroll
      for (int r = 0; r < 4; ++r){
        const float* gib = gi + (size_t)(mrow0 + lr0 + r) * 1536;
        giv0[r] = gib[col]; giv1[r] = gib[512 + col]; giv2[r] = gib[1024 + col];
      }
      f32x4 aR = {0,0,0,0}, aZ = {0,0,0,0}, aN = {0,0,0,0};
      for (int k0 = 0; k0 < 512; k0 += 32){
        bf16x8 af = afrag(k0);
        aR = mfma16(af, ldb(a.Whh0, j0,        k0, lane), aR);
        aZ = mfma16(af, ldb(a.Whh0, 512 + j0,  k0, lane), aZ);
        aN = mfma16(af, ldb(a.Whh0, 1024 + j0, k0, lane), aN);
      }
      #pragma unroll
      for (int r = 0; r < 4; ++r){
        int lr = lr0 + r;
        float rr = sigm(giv0[r] + aR[r] + a.bhh0[col]);
        float zz = sigm(giv1[r] + aZ[r] + a.bhh0[512 + col]);
        float nn = ftanh(giv2[r] + rr * (aN[r] + a.bhh0[1024 + col]));
        float hp = bf2f((short)sH[lr * 520 + col]);
        sOut[lr * 64 + lcol] = (1.f - zz) * nn + zz * hp;
      }
      __syncthreads();
      packstore(a.h1_bf, mrow0, jbase);
      // split-K q partial: qpart[cg][rows][n] = h1_slice @ Whid2ctx[:, jbase:jbase+64]^T
      bf16x8 qa0, qa1;
      #pragma unroll
      for (int j = 0; j < 8; ++j){
        qa0[j] = f2bf(sOut[(lane & 15) * 64 +      ((lane >> 4) << 3) + j]);
        qa1[j] = f2bf(sOut[(lane & 15) * 64 + 32 + ((lane >> 4) << 3) + j]);
      }
      #pragma unroll
      for (int nt = 0; nt < 8; ++nt){
        int n0 = (wv << 7) + (nt << 4);
        f32x4 qacc = {0,0,0,0};
        qacc = mfma16(qa0, ldb(a.Whid2ctx, n0, jbase,      lane), qacc);
        qacc = mfma16(qa1, ldb(a.Whid2ctx, n0, jbase + 32, lane), qacc);
        int qcol = n0 + (lane & 15);
        #pragma unroll
        for (int r = 0; r < 4; ++r)
          astf(a.qpart + (size_t)(cg * 64 + mrow0 + lr0 + r) * 512 + qcol, qacc[r]);
      }
      __syncthreads();
      sig(a.barA, wg, tok);
      // ---- attention for b = wg ----
      waitslots(a.barA, abase, 8, tok);
      attention(batt);
      __syncthreads();
      sig(a.barC, batt, tok);
    }
  } else if (wg < 64){
    // ---- Group B: gh1 in registers (parallel with attention), then P3 ----
    const int g = wg - 32;
    const int rg = g >> 3, cg = g & 7;
    const int mrow0 = rg << 4, jbase = cg << 6;
    const int j0 = jbase + (wv << 4);
    const int col = j0 + (lane & 15), lcol = col - jbase;
    const int lr0 = (lane >> 4) << 2;
    #pragma unroll 1
    for (int t = 0; t < 48; ++t){
      const u32 tok = t + 1;
      // h1 ready: 8 same-row-group A WGs
      waitslots(a.barA, rg << 3, 8, tok);
      burst16(a.h1_bf, mrow0);
      f32x4 hR = {0,0,0,0}, hZ = {0,0,0,0}, hN = {0,0,0,0};
      for (int k0 = 0; k0 < 512; k0 += 32){
        bf16x8 af = afrag(k0);
        hR = mfma16(af, ldb(a.Whh1, j0,        k0, lane), hR);
        hZ = mfma16(af, ldb(a.Whh1, 512 + j0,  k0, lane), hZ);
        hN = mfma16(af, ldb(a.Whh1, 1024 + j0, k0, lane), hN);
      }
      // save h1 values needed for the z-blend before sH is overwritten by catt
      float hp4[4];
      #pragma unroll
      for (int r = 0; r < 4; ++r) hp4[r] = bf2f((short)sH[(lr0 + r) * 520 + col]);
      // catt ready: only the 16 attention WGs covering our rows
      waitslots(a.barC, mrow0, 16, tok);
      burst16(a.catt_bf, mrow0);
      f32x4 iR = {0,0,0,0}, iZ = {0,0,0,0}, iN = {0,0,0,0};
      for (int k0 = 0; k0 < 512; k0 += 32){
        bf16x8 af = afrag(k0);
        iR = mfma16(af, ldb(a.Wcomb, j0,        k0, lane), iR);
        iZ = mfma16(af, ldb(a.Wcomb, 512 + j0,  k0, lane), iZ);
        iN = mfma16(af, ldb(a.Wcomb, 1024 + j0, k0, lane), iN);
      }
      float* h2t = a.h2 + (size_t)t * 32768;
      #pragma unroll
      for (int r = 0; r < 4; ++r){
        int lr = lr0 + r, b = mrow0 + lr;
        float rr = sigm(iR[r] + a.bih1[col]        + hR[r] + a.bhh1[col]);
        float zz = sigm(iZ[r] + a.bih1[512 + col]  + hZ[r] + a.bhh1[512 + col]);
        float nn = ftanh(iN[r] + a.bih1[1024 + col] + rr * (hN[r] + a.bhh1[1024 + col]));
        float hv = (1.f - zz) * nn + zz * hp4[r];
        h2t[(size_t)b * 512 + col] = hv;
        sOut[lr * 64 + lcol] = hv;
      }
      __syncthreads();
      packstore(a.h_bf, mrow0, jbase);
      __syncthreads();
      sig(a.barD, g, tok);
    }
  } else {
    // ---- Group C: attention for b = 32..63 ----
    const int b = wg - 32;               // wg 64..95 -> b 32..63
    const int abase = (b >> 4) << 3;
    #pragma unroll 1
    for (int t = 0; t < 48; ++t){
      const u32 tok = t + 1;
      waitslots(a.barA, abase, 8, tok);
      attention(b);
      __syncthreads();
      sig(a.barC, b, tok);
    }
  }
}

// ---------------- phase 2 ----------------

__global__ __launch_bounds__(256) void k_logit(const float* __restrict__ A, const short* __restrict__ W,
                                               const float* __restrict__ bias, short* __restrict__ tlb,
                                               float* __restrict__ tlf){
  int wg = blockIdx.x * 4 + (threadIdx.x >> 6);
  int lane = threadIdx.x & 63;
  int mt = wg >> 5, nt = wg & 31;
  int m0 = mt << 4, n0 = nt << 4;
  f32x4 acc = {0.f, 0.f, 0.f, 0.f};
  for (int k = 0; k < 512; k += 32)
    acc = mfma16(load_a32(A, 512, m0, k, lane), ldb(W, n0, k, lane), acc);
  int col = n0 + (lane & 15);
  int r0 = m0 + ((lane >> 4) << 2);
  #pragma unroll
  for (int r = 0; r < 4; ++r){
    float v = ftanh(acc[r] + bias[col]);
    size_t o = (size_t)(r0 + r) * 512 + col;
    tlf[o] = v; tlb[o] = f2bf(v);
  }
}

__global__ __launch_bounds__(256) void k_sumexp(const short* __restrict__ A, const short* __restrict__ B,
                                                const float* __restrict__ bias, float* __restrict__ sumexp){
  __shared__ short lA[128 * 40];
  __shared__ short lB[128 * 40];
  int bm = blockIdx.x % 24, bn = blockIdx.x / 24;
  int m0 = bm * 128, n0 = bn * 128;
  int tid = threadIdx.x, w = tid >> 6, lane = tid & 63;
  int mq = (w >> 1) * 64, nq = (w & 1) * 64;
  f32x4 acc[4][4];
  #pragma unroll
  for (int i = 0; i < 4; ++i)
    #pragma unroll
    for (int j = 0; j < 4; ++j) acc[i][j] = (f32x4){0.f, 0.f, 0.f, 0.f};

  for (int k0 = 0; k0 < 512; k0 += 32){
    __syncthreads();
    #pragma unroll
    for (int i = 0; i < 2; ++i){
      int idx = tid * 8 + i * 2048;
      int row = idx >> 5, colh = idx & 31;
      *(bf16x8*)&lA[row * 40 + colh] = *(const bf16x8*)(A + (size_t)(m0 + row) * 512 + k0 + colh);
      *(bf16x8*)&lB[row * 40 + colh] = *(const bf16x8*)(B + (size_t)(n0 + row) * 512 + k0 + colh);
    }
    __syncthreads();
    bf16x8 af[4], bfr[4];
    #pragma unroll
    for (int x = 0; x < 4; ++x){
      af[x]  = *(const bf16x8*)&lA[(mq + x * 16 + (lane & 15)) * 40 + ((lane >> 4) << 3)];
      bfr[x] = *(const bf16x8*)&lB[(nq + x * 16 + (lane & 15)) * 40 + ((lane >> 4) << 3)];
    }
    #pragma unroll
    for (int mi = 0; mi < 4; ++mi)
      #pragma unroll
      for (int ni = 0; ni < 4; ++ni)
        acc[mi][ni] = mfma16(af[mi], bfr[ni], acc[mi][ni]);
  }

  #pragma unroll
  for (int mi = 0; mi < 4; ++mi){
    #pragma unroll
    for (int r = 0; r < 4; ++r){
      float e = 0.f;
      #pragma unroll
      for (int ni = 0; ni < 4; ++ni){
        int col = n0 + nq + ni * 16 + (lane & 15);
        e += __expf(acc[mi][ni][r] + bias[col]);
      }
      e += __shfl_xor(e, 1, 64); e += __shfl_xor(e, 2, 64);
      e += __shfl_xor(e, 4, 64); e += __shfl_xor(e, 8, 64);
      if ((lane & 15) == 0){
        int row = m0 + mq + mi * 16 + ((lane >> 4) << 2) + r;
        atomicAdd(&sumexp[row], e);
      }
    }
  }
}

__global__ __launch_bounds__(256) void k_loss(const float* __restrict__ tlf, const float* __restrict__ Wop,
                                              const float* __restrict__ bop, const int* __restrict__ y,
                                              const float* __restrict__ sumexp, float* __restrict__ loss){
  int step = blockIdx.x;
  int w = threadIdx.x >> 6, lane = threadIdx.x & 63;
  __shared__ float accw[4];
  float part = 0.f;
  for (int b = w; b < 64; b += 4){
    int row = step * 64 + b;
    int t = y[(step + 1) * 64 + b];
    if (t != 0){
      const float* a = tlf + (size_t)row * 512 + lane * 8;
      const float* wr = Wop + (size_t)t * 512 + lane * 8;
      float d = 0.f;
      #pragma unroll
      for (int j = 0; j < 8; ++j) d += a[j] * wr[j];
      d = wsum(d);
      if (lane == 0) part += d + bop[t] - __logf(sumexp[row]);
    }
  }
  if (lane == 0) accw[w] = part;
  __syncthreads();
  if (threadIdx.x == 0) atomicAdd(loss, -(accw[0] + accw[1] + accw[2] + accw[3]));
}

__global__ void k_final(const float* __restrict__ loss, float* __restrict__ out){
  if (threadIdx.x == 0 && blockIdx.x == 0) out[0] = loss[0];
}

// ---------------- host launch ----------------

extern "C" void kernel_launch(void* const* d_in, const int* in_sizes, int n_in,
                              void* d_out, int out_size, void* d_ws, size_t ws_size,
                              hipStream_t stream) {
  const float* ctx       = (const float*)d_in[0];
  const float* ctx_mask  = (const float*)d_in[1];
  const float* txt_ctx   = (const float*)d_in[2];
  const int*   y         = (const int*)d_in[3];
  const float* emb       = (const float*)d_in[4];
  const float* W_ctx2ctx = (const float*)d_in[5];
  const float* W_hid2ctx = (const float*)d_in[6];
  const float* w_mlp     = (const float*)d_in[7];
  const float* W_ctx2hid = (const float*)d_in[8];
  const float* W_dec_init= (const float*)d_in[9];
  const float* W_ih0     = (const float*)d_in[10];
  const float* W_hh0     = (const float*)d_in[11];
  const float* b_ih0     = (const float*)d_in[12];
  const float* b_hh0     = (const float*)d_in[13];
  const float* W_ih1     = (const float*)d_in[14];
  const float* W_hh1     = (const float*)d_in[15];
  const float* b_ih1     = (const float*)d_in[16];
  const float* b_hh1     = (const float*)d_in[17];
  const float* W_hid2out = (const float*)d_in[18];
  const float* b_hid2out = (const float*)d_in[19];
  const float* W_out2prob= (const float*)d_in[20];
  const float* b_out2prob= (const float*)d_in[21];
  float* out = (float*)d_out;

  char* p = (char*)d_ws;
  auto alloc = [&](size_t n){ char* r = p; p += (n + 255) & ~(size_t)255; return r; };
  short* Wb_hh0     = (short*)alloc((size_t)1536 * 512 * 2);
  short* Wb_hid2ctx = (short*)alloc((size_t)512 * 512 * 2);
  short* Wb_hh1     = (short*)alloc((size_t)1536 * 512 * 2);
  short* Wb_hid2out = (short*)alloc((size_t)512 * 512 * 2);
  short* Wb_dec     = (short*)alloc((size_t)512 * 512 * 2);
  short* Wb_c2c     = (short*)alloc((size_t)512 * 512 * 2);
  short* Wb_ih0     = (short*)alloc((size_t)1536 * 512 * 2);
  short* Wb_o2p     = (short*)alloc((size_t)32000 * 512 * 2);
  short* WctT       = (short*)alloc((size_t)512 * 512 * 2);
  short* Wb_comb    = (short*)alloc((size_t)1536 * 512 * 2);
  short* ctx_projbf = (short*)alloc((size_t)4096 * 512 * 2);
  float* gi0_all    = (float*)alloc((size_t)3072 * 1536 * 4);
  float* mixed      = (float*)alloc((size_t)64 * 512 * 4);
  float* h0buf      = (float*)alloc((size_t)64 * 512 * 4);
  unsigned short* h_bf    = (unsigned short*)alloc((size_t)64 * 512 * 2);
  unsigned short* h1_bf   = (unsigned short*)alloc((size_t)64 * 512 * 2);
  unsigned short* catt_bf = (unsigned short*)alloc((size_t)64 * 512 * 2);
  float* qpart      = (float*)alloc((size_t)8 * 64 * 512 * 4);
  float* h2_all     = (float*)alloc((size_t)3072 * 512 * 4);
  short* tl_bf      = (short*)alloc((size_t)3072 * 512 * 2);
  float* tl_f       = (float*)alloc((size_t)3072 * 512 * 4);
  // zero region: sumexp(3072) + loss(1) + 3 barrier arrays (64*SLOT each)
  int nbar = 3 * 64 * SLOT;
  float* zreg       = (float*)alloc((size_t)(3073 + nbar) * 4);
  float* sumexp     = zreg;
  float* lossbuf    = zreg + 3072;
  u32* barA         = (u32*)(zreg + 3073);
  u32* barC         = barA + 64 * SLOT;
  u32* barD         = barC + 64 * SLOT;

  dim3 blk(256);
  // ---- phase 0 ----
  CvtJobs jb;
  const float* srcs[8] = {W_hh0, W_hid2ctx, W_hh1, W_hid2out, W_dec_init, W_ctx2ctx, W_ih0, W_out2prob};
  short* dsts[8] = {Wb_hh0, Wb_hid2ctx, Wb_hh1, Wb_hid2out, Wb_dec, Wb_c2c, Wb_ih0, Wb_o2p};
  int sizes4[8] = {1536*512/4, 512*512/4, 1536*512/4, 512*512/4, 512*512/4, 512*512/4, 1536*512/4, 32000*512/4};
  int cum = 0;
  for (int i = 0; i < 8; ++i){ jb.src[i] = srcs[i]; jb.dst[i] = dsts[i]; jb.cum4[i] = cum; cum += sizes4[i]; }
  jb.cum4[8] = cum;
  k_cvt_multi<<<dim3((cum + 255) / 256), blk, 0, stream>>>(jb, cum);
  k_tc<<<dim3(1024), blk, 0, stream>>>(W_ctx2hid, WctT);
  k_gemm_bt_obf<<<dim3(768), blk, 0, stream>>>(W_ih1, WctT, Wb_comb, 512);       // W_comb 1536x512
  k_meanmix<<<dim3(128), blk, 0, stream>>>(ctx, ctx_mask, txt_ctx, mixed);
  k_gemm_bt<<<dim3(32), blk, 0, stream>>>(mixed, Wb_dec, h0buf, 512, 1);         // h0 = tanh(.)
  k_pack_h0<<<dim3(64), blk, 0, stream>>>(h0buf, (u32*)h_bf);
  k_gemm_bt_obf<<<dim3(2048), blk, 0, stream>>>(ctx, Wb_c2c, ctx_projbf, 512);   // ctx_proj bf16
  k_gi0<<<dim3(4608), blk, 0, stream>>>(y, emb, Wb_ih0, b_ih0, gi0_all);
  k_zero<<<dim3((3073 + nbar + 255) / 256), blk, 0, stream>>>(zreg, 3073 + nbar);

  // ---- phase 1: persistent kernel, neighbor-only scattered-slot waits ----
  RB rb;
  rb.gi0 = gi0_all;
  rb.Whh0 = Wb_hh0; rb.bhh0 = b_hh0;
  rb.Whid2ctx = Wb_hid2ctx;
  rb.Whh1 = Wb_hh1; rb.bhh1 = b_hh1;
  rb.Wcomb = Wb_comb; rb.bih1 = b_ih1;
  rb.ctx_proj = ctx_projbf; rb.ctx = ctx; rb.mask = ctx_mask; rb.wmlp = w_mlp;
  rb.h_bf = h_bf; rb.h1_bf = h1_bf; rb.catt_bf = catt_bf;
  rb.qpart = qpart; rb.h2 = h2_all;
  rb.barA = barA; rb.barC = barC; rb.barD = barD;
  void* kargs[] = { &rb };
  hipLaunchCooperativeKernel((const void*)k_recur, dim3(96), blk, kargs, 0, stream);

  // ---- phase 2 ----
  k_logit<<<dim3(1536), blk, 0, stream>>>(h2_all, Wb_hid2out, b_hid2out, tl_bf, tl_f);
  k_sumexp<<<dim3(6000), blk, 0, stream>>>(tl_bf, Wb_o2p, b_out2prob, sumexp);
  k_loss<<<dim3(48), blk, 0, stream>>>(tl_f, W_out2prob, b_out2prob, y, sumexp, lossbuf);
  k_final<<<dim3(1), blk, 0, stream>>>(lossbuf, out);
}

// Round 2
// 2552.060 us; speedup vs baseline: 1.2725x; 1.0818x over previous
//
#include <hip/hip_runtime.h>
#include <stdint.h>

// S=64, B=64, C=H=E=512, V=32000, steps T=48
// Phase 1: ONE persistent kernel (96 WGs), 3 sub-phases/step on the critical path:
//   Group A (WG 0-31):  P0: gru0 -> h1 (bf16 packed) + split-K q-partials, then
//                       attention for b=wg
//   Group B (WG 32-63): gh1 in REGISTERS (off critical path), then P3:
//                       gi1 = catt@Wcomb^T + combine -> h2 (fp32 + bf16 packed)
//   Group C (WG 64-95): attention for b=32..63
// Sync: scattered per-WG token slots, NEIGHBOR-ONLY waits (8/16 slots = true deps),
// s_sleep(1) polling. 3 handoffs/step (barD -> barA -> barC).
// This round: shuffle-free attention score reduce (LDS transpose), t-invariant
// bias/mask/wmlp hoisting, loop-carried gi0 prefetch, XCD-swizzled k_sumexp.

using bf16x8 = __attribute__((ext_vector_type(8))) short;
using f32x4  = __attribute__((ext_vector_type(4))) float;
using s16x4  = __attribute__((ext_vector_type(4))) short;
typedef unsigned long long u64;
typedef unsigned int u32;

#define DI __device__ __forceinline__

DI short f2bf(float x){
  union { float f; uint32_t u; } v; v.f = x;
  uint32_t r = (v.u + 0x7FFFu + ((v.u >> 16) & 1u)) >> 16;
  return (short)r;
}
DI float bf2f(short s){
  union { uint32_t u; float f; } v; v.u = ((uint32_t)(unsigned short)s) << 16; return v.f;
}
DI float sigm(float x){ return __fdividef(1.f, 1.f + __expf(-x)); }
DI float ftanh(float x){ return 1.f - __fdividef(2.f, __expf(2.f*x) + 1.f); }
DI float wsum(float v){
  #pragma unroll
  for (int m = 32; m > 0; m >>= 1) v += __shfl_xor(v, m, 64);
  return v;
}
DI f32x4 mfma16(bf16x8 a, bf16x8 b, f32x4 c){
  return __builtin_amdgcn_mfma_f32_16x16x32_bf16(a, b, c, 0, 0, 0);
}

// AGENT-scope atomics (reach/observe coherence point; no local stale copies)
DI u32  ald32(const u32* p){ return __hip_atomic_load(p, __ATOMIC_RELAXED, __HIP_MEMORY_SCOPE_AGENT); }
DI void ast32(u32* p, u32 v){ __hip_atomic_store(p, v, __ATOMIC_RELAXED, __HIP_MEMORY_SCOPE_AGENT); }
DI u64  ald64(const u64* p){ return __hip_atomic_load(p, __ATOMIC_RELAXED, __HIP_MEMORY_SCOPE_AGENT); }
DI void ast64(u64* p, u64 v){ __hip_atomic_store(p, v, __ATOMIC_RELAXED, __HIP_MEMORY_SCOPE_AGENT); }
DI float aldf(const float* p){ return __hip_atomic_load(p, __ATOMIC_RELAXED, __HIP_MEMORY_SCOPE_AGENT); }
DI void astf(float* p, float v){ __hip_atomic_store(p, v, __ATOMIC_RELAXED, __HIP_MEMORY_SCOPE_AGENT); }

// plain bf16 weight fragment (row-major [N][512])
DI bf16x8 ldb(const short* __restrict__ W, int n0, int k0, int lane){
  return *(const bf16x8*)(W + (size_t)(n0 + (lane & 15)) * 512 + k0 + ((lane >> 4) << 3));
}

#define SLOT 64   // dwords per token slot (256 B padding)

// signal: call AFTER __syncthreads() (compiler drains vmcnt before s_barrier)
DI void sig(u32* arr, int slot, u32 tok){
  if (threadIdx.x == 0){
    __builtin_amdgcn_s_waitcnt(0);
    ast32(arr + slot * SLOT, tok);
  }
}
// wait: lane i (<cnt) polls slot base+i; all-ballot; then block barrier
DI void waitslots(const u32* arr, int base, int cnt, u32 tok){
  if (threadIdx.x < 64){
    for (;;){
      u32 v = (threadIdx.x < cnt) ? ald32(arr + (base + threadIdx.x) * SLOT) : tok;
      if (__all((int)(v - tok) >= 0)) break;
      __builtin_amdgcn_s_sleep(1);
    }
  }
  __syncthreads();
}

// ---------------- elementwise / prep kernels ----------------

struct CvtJobs { const float* src[8]; short* dst[8]; int cum4[9]; };

__global__ __launch_bounds__(256) void k_cvt_multi(CvtJobs jb, int total4){
  int i = blockIdx.x * 256 + threadIdx.x;
  if (i >= total4) return;
  int j = 0;
  #pragma unroll
  for (int k = 0; k < 8; ++k) if (i >= jb.cum4[k + 1]) j = k + 1;
  int off = i - jb.cum4[j];
  float4 v = ((const float4*)jb.src[j])[off];
  s16x4 o; o[0] = f2bf(v.x); o[1] = f2bf(v.y); o[2] = f2bf(v.z); o[3] = f2bf(v.w);
  ((s16x4*)jb.dst[j])[off] = o;
}

__global__ __launch_bounds__(256) void k_tc(const float* __restrict__ W, short* __restrict__ WT){
  int i = blockIdx.x * 256 + threadIdx.x;
  int c = i >> 9, h = i & 511;
  WT[i] = f2bf(W[h * 512 + c]);
}

__global__ __launch_bounds__(256) void k_zero(float* __restrict__ p, int n){
  int i = blockIdx.x * 256 + threadIdx.x;
  if (i < n) p[i] = 0.f;
}

__global__ __launch_bounds__(256) void k_meanmix(const float* __restrict__ ctx, const float* __restrict__ mask,
                                                 const float* __restrict__ txt, float* __restrict__ mixed){
  int i = blockIdx.x * 256 + threadIdx.x;
  int b = i >> 9, c = i & 511;
  float s = 0.f;
  for (int t = 0; t < 64; ++t) s += ctx[(size_t)(t * 64 + b) * 512 + c];
  float dn = 0.f;
  for (int t = 0; t < 64; ++t) dn += mask[t * 64 + b];
  mixed[i] = 0.5f * (s / dn) + 0.5f * txt[i];
}

// pack h0 fp32 -> bf16 packed
__global__ __launch_bounds__(256) void k_pack_h0(const float* __restrict__ h0, u32* __restrict__ hbf){
  int i = blockIdx.x * 256 + threadIdx.x;   // 0..16383
  u32 lo = (u32)(unsigned short)f2bf(h0[2 * i]);
  u32 hi = (u32)(unsigned short)f2bf(h0[2 * i + 1]);
  hbf[i] = lo | (hi << 16);
}

// ---------------- generic wave-tile GEMMs (K = 512, fp32 A) ----------------

DI bf16x8 load_a32(const float* __restrict__ A, int ld, int m0, int k0, int lane){
  const float* p = A + (size_t)(m0 + (lane & 15)) * ld + k0 + ((lane >> 4) << 3);
  bf16x8 f;
  #pragma unroll
  for (int j = 0; j < 8; ++j) f[j] = f2bf(p[j]);
  return f;
}

__global__ __launch_bounds__(256) void k_gemm_bt(const float* __restrict__ A, const short* __restrict__ W,
                                                 float* __restrict__ C, int N, int act){
  int wg = blockIdx.x * 4 + (threadIdx.x >> 6);
  int lane = threadIdx.x & 63;
  int ntiles = N >> 4;
  int mt = wg / ntiles, nt = wg - mt * ntiles;
  int m0 = mt << 4, n0 = nt << 4;
  f32x4 acc = {0.f, 0.f, 0.f, 0.f};
  for (int k = 0; k < 512; k += 32)
    acc = mfma16(load_a32(A, 512, m0, k, lane), ldb(W, n0, k, lane), acc);
  int col = n0 + (lane & 15);
  int r0 = m0 + ((lane >> 4) << 2);
  #pragma unroll
  for (int r = 0; r < 4; ++r){
    float v = acc[r];
    if (act) v = ftanh(v);
    C[(size_t)(r0 + r) * N + col] = v;
  }
}

__global__ __launch_bounds__(256) void k_gemm_bt_obf(const float* __restrict__ A, const short* __restrict__ W,
                                                     short* __restrict__ C, int N){
  int wg = blockIdx.x * 4 + (threadIdx.x >> 6);
  int lane = threadIdx.x & 63;
  int ntiles = N >> 4;
  int mt = wg / ntiles, nt = wg - mt * ntiles;
  int m0 = mt << 4, n0 = nt << 4;
  f32x4 acc = {0.f, 0.f, 0.f, 0.f};
  for (int k = 0; k < 512; k += 32)
    acc = mfma16(load_a32(A, 512, m0, k, lane), ldb(W, n0, k, lane), acc);
  int col = n0 + (lane & 15);
  int r0 = m0 + ((lane >> 4) << 2);
  #pragma unroll
  for (int r = 0; r < 4; ++r)
    C[(size_t)(r0 + r) * N + col] = f2bf(acc[r]);
}

__global__ __launch_bounds__(256) void k_gi0(const int* __restrict__ y, const float* __restrict__ emb,
                                             const short* __restrict__ W, const float* __restrict__ bias,
                                             float* __restrict__ C){
  int wg = blockIdx.x * 4 + (threadIdx.x >> 6);
  int lane = threadIdx.x & 63;
  int mt = wg / 96, nt = wg - mt * 96;
  int m0 = mt << 4, n0 = nt << 4;
  int yr = y[m0 + (lane & 15)];
  const float* arow = emb + (size_t)yr * 512;
  f32x4 acc = {0.f, 0.f, 0.f, 0.f};
  for (int k = 0; k < 512; k += 32){
    const float* p = arow + k + ((lane >> 4) << 3);
    bf16x8 a;
    #pragma unroll
    for (int j = 0; j < 8; ++j) a[j] = f2bf(p[j]);
    acc = mfma16(a, ldb(W, n0, k, lane), acc);
  }
  int col = n0 + (lane & 15);
  int r0 = m0 + ((lane >> 4) << 2);
  #pragma unroll
  for (int r = 0; r < 4; ++r)
    C[(size_t)(r0 + r) * 1536 + col] = acc[r] + bias[col];
}

// ---------------- persistent recurrence kernel ----------------

struct RB {
  const float* gi0;        // [48][64][1536] fp32 (incl b_ih0)
  const short* Whh0; const float* bhh0;
  const short* Whid2ctx;   // bf16 [512][512]
  const short* Whh1; const float* bhh1;
  const short* Wcomb; const float* bih1;
  const short* ctx_proj;   // bf16 [s*64+b][512]
  const float* ctx;        // fp32 [s*64+b][512]
  const float* mask;       // [64][64] (s,b)
  const float* wmlp;       // [512]
  unsigned short* h_bf;    // [64][512] bf16 (recurrent state)
  unsigned short* h1_bf;   // [64][512] bf16
  unsigned short* catt_bf; // [64][512] bf16
  float* qpart;            // [8 cg][64 b][512] fp32 split-K q partials
  float* h2;               // [48][64][512] fp32 (plain, for phase 2)
  u32* barA; u32* barC; u32* barD;  // token slots, stride SLOT
};

__global__ __launch_bounds__(256, 1) void k_recur(RB a){
  // sH/sOut (GEMM phases) and pl (attention score partials) overlay the same LDS:
  // within a WG's timeline they are never live simultaneously.
  __shared__ char smem[16 * 520 * 2 + 16 * 64 * 4];
  unsigned short* sH = (unsigned short*)smem;            // [16][520] bf16 burst tile
  float* sOut = (float*)(smem + 16 * 520 * 2);           // [16][64]
  float* pl   = (float*)smem;                            // [64][65] score partials
  __shared__ float qs[512];
  __shared__ float al[64];
  const int wg = blockIdx.x, tid = threadIdx.x;
  const int wv = tid >> 6, lane = tid & 63;

  // burst 16 rows x 512 bf16 into sH
  auto burst16 = [&](const unsigned short* src, int row0){
    #pragma unroll
    for (int i = 0; i < 8; ++i){
      int idx = tid + i * 256;              // 0..2047
      int r = idx >> 7, c4 = idx & 127;     // 128 b64-chunks per row
      u64 v = ald64((const u64*)(src + (size_t)(row0 + r) * 512) + c4);
      *(u64*)(sH + r * 520 + c4 * 4) = v;
    }
    __syncthreads();
  };
  auto afrag = [&](int k0) -> bf16x8 {
    return *(const bf16x8*)(sH + (lane & 15) * 520 + k0 + ((lane >> 4) << 3));
  };
  auto packstore = [&](unsigned short* dst, int mrow0, int jbase){
    int r = tid >> 4, ch = tid & 15;
    float4 v = *(const float4*)&sOut[r * 64 + ch * 4];
    u64 pk = (u64)(unsigned short)f2bf(v.x)
           | ((u64)(unsigned short)f2bf(v.y) << 16)
           | ((u64)(unsigned short)f2bf(v.z) << 32)
           | ((u64)(unsigned short)f2bf(v.w) << 48);
    ast64((u64*)(dst + (size_t)(mrow0 + r) * 512 + jbase + ch * 4), pk);
  };
  // attention for batch element b: sum split-K q partials, shuffle-free score
  // reduce via pl[64][65] transpose, fused mask+softmax, weighted ctx sum.
  auto attention = [&](int b, float maskv, const float (&w8)[8]){
    float q0 = 0.f, q1 = 0.f;
    #pragma unroll
    for (int cgi = 0; cgi < 8; ++cgi){
      u64 v = ald64((const u64*)(a.qpart + (size_t)(cgi * 64 + b) * 512) + tid);
      union { u64 u; float f[2]; } cv; cv.u = v;
      q0 += cv.f[0]; q1 += cv.f[1];
    }
    qs[2 * tid] = q0; qs[2 * tid + 1] = q1;
    __syncthreads();
    float q8[8];
    #pragma unroll
    for (int j = 0; j < 8; ++j) q8[j] = qs[lane * 8 + j];
    for (int i = 0; i < 16; ++i){
      int s = (wv << 4) + i;
      bf16x8 c8 = *(const bf16x8*)(a.ctx_proj + (size_t)((s << 6) + b) * 512 + lane * 8);
      float p = 0.f;
      #pragma unroll
      for (int j = 0; j < 8; ++j)
        p += ftanh(bf2f(c8[j]) + q8[j]) * w8[j];
      pl[s * 65 + lane] = p;
    }
    __syncthreads();
    if (tid < 64){
      const float* row = pl + tid * 65;
      float v0 = 0.f, v1 = 0.f, v2 = 0.f, v3 = 0.f;
      #pragma unroll
      for (int j = 0; j < 64; j += 4){
        v0 += row[j]; v1 += row[j + 1]; v2 += row[j + 2]; v3 += row[j + 3];
      }
      float v = (v0 + v1) + (v2 + v3);
      v = (maskv > 0.f) ? v : -100000000.0f;
      float mx = v;
      #pragma unroll
      for (int m = 32; m > 0; m >>= 1) mx = fmaxf(mx, __shfl_xor(mx, m, 64));
      float e = __expf(v - mx);
      float se = e;
      #pragma unroll
      for (int m = 32; m > 0; m >>= 1) se += __shfl_xor(se, m, 64);
      al[tid] = e / se;
    }
    __syncthreads();
    float s0 = 0.f, s1 = 0.f;
    int c0 = tid * 2;
    for (int s = 0; s < 64; ++s){
      float2 cv = *(const float2*)(a.ctx + (size_t)((s << 6) + b) * 512 + c0);
      s0 += al[s] * cv.x; s1 += al[s] * cv.y;
    }
    u32 pk = (u32)(unsigned short)f2bf(s0) | ((u32)(unsigned short)f2bf(s1) << 16);
    ast32((u32*)a.catt_bf + (size_t)b * 256 + tid, pk);
  };

  if (wg < 32){
    // ---- Group A: P0 (gru0 + split-K q partials), then attention b=wg ----
    const int rg = wg >> 3, cg = wg & 7;
    const int mrow0 = rg << 4, jbase = cg << 6;
    const int j0 = jbase + (wv << 4);
    const int col = j0 + (lane & 15), lcol = col - jbase;
    const int lr0 = (lane >> 4) << 2;
    const int batt = wg;
    const int abase = (batt >> 4) << 3;   // barA slots of row-group producing q for batt
    // t-invariant hoists
    const float bh0r = a.bhh0[col], bh0z = a.bhh0[512 + col], bh0n = a.bhh0[1024 + col];
    float w8[8];
    #pragma unroll
    for (int j = 0; j < 8; ++j) w8[j] = a.wmlp[lane * 8 + j];
    const float maskv = (tid < 64) ? a.mask[(tid << 6) + batt] : 0.f;
    // loop-carried gi0 prefetch (completes during the barD wait)
    float g0[4], g1[4], g2[4];
    {
      const float* gi = a.gi0;
      #pragma unroll
      for (int r = 0; r < 4; ++r){
        const float* gib = gi + (size_t)(mrow0 + lr0 + r) * 1536;
        g0[r] = gib[col]; g1[r] = gib[512 + col]; g2[r] = gib[1024 + col];
      }
    }
    #pragma unroll 1
    for (int t = 0; t < 48; ++t){
      const u32 tok = t + 1;
      // ---- P0: gru0 ----
      waitslots(a.barD, rg << 3, 8, (u32)t);
      burst16(a.h_bf, mrow0);
      f32x4 aR = {0,0,0,0}, aZ = {0,0,0,0}, aN = {0,0,0,0};
      for (int k0 = 0; k0 < 512; k0 += 32){
        bf16x8 af = afrag(k0);
        aR = mfma16(af, ldb(a.Whh0, j0,        k0, lane), aR);
        aZ = mfma16(af, ldb(a.Whh0, 512 + j0,  k0, lane), aZ);
        aN = mfma16(af, ldb(a.Whh0, 1024 + j0, k0, lane), aN);
      }
      #pragma unroll
      for (int r = 0; r < 4; ++r){
        int lr = lr0 + r;
        float rr = sigm(g0[r] + aR[r] + bh0r);
        float zz = sigm(g1[r] + aZ[r] + bh0z);
        float nn = ftanh(g2[r] + rr * (aN[r] + bh0n));
        float hp = bf2f((short)sH[lr * 520 + col]);
        sOut[lr * 64 + lcol] = (1.f - zz) * nn + zz * hp;
      }
      __syncthreads();
      packstore(a.h1_bf, mrow0, jbase);
      // split-K q partial: qpart[cg][rows][n] = h1_slice @ Whid2ctx[:, jbase:jbase+64]^T
      bf16x8 qa0, qa1;
      #pragma unroll
      for (int j = 0; j < 8; ++j){
        qa0[j] = f2bf(sOut[(lane & 15) * 64 +      ((lane >> 4) << 3) + j]);
        qa1[j] = f2bf(sOut[(lane & 15) * 64 + 32 + ((lane >> 4) << 3) + j]);
      }
      #pragma unroll
      for (int nt = 0; nt < 8; ++nt){
        int n0 = (wv << 7) + (nt << 4);
        f32x4 qacc = {0,0,0,0};
        qacc = mfma16(qa0, ldb(a.Whid2ctx, n0, jbase,      lane), qacc);
        qacc = mfma16(qa1, ldb(a.Whid2ctx, n0, jbase + 32, lane), qacc);
        int qcol = n0 + (lane & 15);
        #pragma unroll
        for (int r = 0; r < 4; ++r)
          astf(a.qpart + (size_t)(cg * 64 + mrow0 + lr0 + r) * 512 + qcol, qacc[r]);
      }
      __syncthreads();
      sig(a.barA, wg, tok);
      // ---- attention for b = wg ----
      waitslots(a.barA, abase, 8, tok);
      attention(batt, maskv, w8);
      __syncthreads();
      sig(a.barC, batt, tok);
      // prefetch next step's gi0 (hides HBM latency under barD wait)
      if (t < 47){
        const float* gi = a.gi0 + (size_t)(t + 1) * 98304;
        #pragma unroll
        for (int r = 0; r < 4; ++r){
          const float* gib = gi + (size_t)(mrow0 + lr0 + r) * 1536;
          g0[r] = gib[col]; g1[r] = gib[512 + col]; g2[r] = gib[1024 + col];
        }
      }
    }
  } else if (wg < 64){
    // ---- Group B: gh1 in registers (parallel with attention), then P3 ----
    const int g = wg - 32;
    const int rg = g >> 3, cg = g & 7;
    const int mrow0 = rg << 4, jbase = cg << 6;
    const int j0 = jbase + (wv << 4);
    const int col = j0 + (lane & 15), lcol = col - jbase;
    const int lr0 = (lane >> 4) << 2;
    // t-invariant hoists (r/z gate biases pre-added)
    const float bcR = a.bih1[col]        + a.bhh1[col];
    const float bcZ = a.bih1[512 + col]  + a.bhh1[512 + col];
    const float biN = a.bih1[1024 + col];
    const float bhN = a.bhh1[1024 + col];
    #pragma unroll 1
    for (int t = 0; t < 48; ++t){
      const u32 tok = t + 1;
      // h1 ready: 8 same-row-group A WGs
      waitslots(a.barA, rg << 3, 8, tok);
      burst16(a.h1_bf, mrow0);
      f32x4 hR = {0,0,0,0}, hZ = {0,0,0,0}, hN = {0,0,0,0};
      for (int k0 = 0; k0 < 512; k0 += 32){
        bf16x8 af = afrag(k0);
        hR = mfma16(af, ldb(a.Whh1, j0,        k0, lane), hR);
        hZ = mfma16(af, ldb(a.Whh1, 512 + j0,  k0, lane), hZ);
        hN = mfma16(af, ldb(a.Whh1, 1024 + j0, k0, lane), hN);
      }
      // save h1 values needed for the z-blend before sH is overwritten by catt
      float hp4[4];
      #pragma unroll
      for (int r = 0; r < 4; ++r) hp4[r] = bf2f((short)sH[(lr0 + r) * 520 + col]);
      // catt ready: only the 16 attention WGs covering our rows
      waitslots(a.barC, mrow0, 16, tok);
      burst16(a.catt_bf, mrow0);
      f32x4 iR = {0,0,0,0}, iZ = {0,0,0,0}, iN = {0,0,0,0};
      for (int k0 = 0; k0 < 512; k0 += 32){
        bf16x8 af = afrag(k0);
        iR = mfma16(af, ldb(a.Wcomb, j0,        k0, lane), iR);
        iZ = mfma16(af, ldb(a.Wcomb, 512 + j0,  k0, lane), iZ);
        iN = mfma16(af, ldb(a.Wcomb, 1024 + j0, k0, lane), iN);
      }
      float* h2t = a.h2 + (size_t)t * 32768;
      #pragma unroll
      for (int r = 0; r < 4; ++r){
        int lr = lr0 + r, b = mrow0 + lr;
        float rr = sigm(iR[r] + hR[r] + bcR);
        float zz = sigm(iZ[r] + hZ[r] + bcZ);
        float nn = ftanh(iN[r] + biN + rr * (hN[r] + bhN));
        float hv = (1.f - zz) * nn + zz * hp4[r];
        h2t[(size_t)b * 512 + col] = hv;
        sOut[lr * 64 + lcol] = hv;
      }
      __syncthreads();
      packstore(a.h_bf, mrow0, jbase);
      __syncthreads();
      sig(a.barD, g, tok);
    }
  } else {
    // ---- Group C: attention for b = 32..63 ----
    const int b = wg - 32;               // wg 64..95 -> b 32..63
    const int abase = (b >> 4) << 3;
    float w8[8];
    #pragma unroll
    for (int j = 0; j < 8; ++j) w8[j] = a.wmlp[lane * 8 + j];
    const float maskv = (tid < 64) ? a.mask[(tid << 6) + b] : 0.f;
    #pragma unroll 1
    for (int t = 0; t < 48; ++t){
      const u32 tok = t + 1;
      waitslots(a.barA, abase, 8, tok);
      attention(b, maskv, w8);
      __syncthreads();
      sig(a.barC, b, tok);
    }
  }
}

// ---------------- phase 2 ----------------

__global__ __launch_bounds__(256) void k_logit(const float* __restrict__ A, const short* __restrict__ W,
                                               const float* __restrict__ bias, short* __restrict__ tlb,
                                               float* __restrict__ tlf){
  int wg = blockIdx.x * 4 + (threadIdx.x >> 6);
  int lane = threadIdx.x & 63;
  int mt = wg >> 5, nt = wg & 31;
  int m0 = mt << 4, n0 = nt << 4;
  f32x4 acc = {0.f, 0.f, 0.f, 0.f};
  for (int k = 0; k < 512; k += 32)
    acc = mfma16(load_a32(A, 512, m0, k, lane), ldb(W, n0, k, lane), acc);
  int col = n0 + (lane & 15);
  int r0 = m0 + ((lane >> 4) << 2);
  #pragma unroll
  for (int r = 0; r < 4; ++r){
    float v = ftanh(acc[r] + bias[col]);
    size_t o = (size_t)(r0 + r) * 512 + col;
    tlf[o] = v; tlb[o] = f2bf(v);
  }
}

__global__ __launch_bounds__(256) void k_sumexp(const short* __restrict__ A, const short* __restrict__ B,
                                                const float* __restrict__ bias, float* __restrict__ sumexp){
  __shared__ short lA[128 * 40];
  __shared__ short lB[128 * 40];
  // bijective XCD swizzle (6000 % 8 == 0): each XCD gets a contiguous chunk of
  // bn-major block order -> B vocab tile fetched ~once per XCD, reused from L2.
  int bid = blockIdx.x;
  int swz = (bid & 7) * 750 + (bid >> 3);
  int bm = swz % 24, bn = swz / 24;
  int m0 = bm * 128, n0 = bn * 128;
  int tid = threadIdx.x, w = tid >> 6, lane = tid & 63;
  int mq = (w >> 1) * 64, nq = (w & 1) * 64;
  f32x4 acc[4][4];
  #pragma unroll
  for (int i = 0; i < 4; ++i)
    #pragma unroll
    for (int j = 0; j < 4; ++j) acc[i][j] = (f32x4){0.f, 0.f, 0.f, 0.f};

  for (int k0 = 0; k0 < 512; k0 += 32){
    __syncthreads();
    #pragma unroll
    for (int i = 0; i < 2; ++i){
      int idx = tid * 8 + i * 2048;
      int row = idx >> 5, colh = idx & 31;
      *(bf16x8*)&lA[row * 40 + colh] = *(const bf16x8*)(A + (size_t)(m0 + row) * 512 + k0 + colh);
      *(bf16x8*)&lB[row * 40 + colh] = *(const bf16x8*)(B + (size_t)(n0 + row) * 512 + k0 + colh);
    }
    __syncthreads();
    bf16x8 af[4], bfr[4];
    #pragma unroll
    for (int x = 0; x < 4; ++x){
      af[x]  = *(const bf16x8*)&lA[(mq + x * 16 + (lane & 15)) * 40 + ((lane >> 4) << 3)];
      bfr[x] = *(const bf16x8*)&lB[(nq + x * 16 + (lane & 15)) * 40 + ((lane >> 4) << 3)];
    }
    #pragma unroll
    for (int mi = 0; mi < 4; ++mi)
      #pragma unroll
      for (int ni = 0; ni < 4; ++ni)
        acc[mi][ni] = mfma16(af[mi], bfr[ni], acc[mi][ni]);
  }

  #pragma unroll
  for (int mi = 0; mi < 4; ++mi){
    #pragma unroll
    for (int r = 0; r < 4; ++r){
      float e = 0.f;
      #pragma unroll
      for (int ni = 0; ni < 4; ++ni){
        int col = n0 + nq + ni * 16 + (lane & 15);
        e += __expf(acc[mi][ni][r] + bias[col]);
      }
      e += __shfl_xor(e, 1, 64); e += __shfl_xor(e, 2, 64);
      e += __shfl_xor(e, 4, 64); e += __shfl_xor(e, 8, 64);
      if ((lane & 15) == 0){
        int row = m0 + mq + mi * 16 + ((lane >> 4) << 2) + r;
        atomicAdd(&sumexp[row], e);
      }
    }
  }
}

__global__ __launch_bounds__(256) void k_loss(const float* __restrict__ tlf, const float* __restrict__ Wop,
                                              const float* __restrict__ bop, const int* __restrict__ y,
                                              const float* __restrict__ sumexp, float* __restrict__ loss){
  int step = blockIdx.x;
  int w = threadIdx.x >> 6, lane = threadIdx.x & 63;
  __shared__ float accw[4];
  float part = 0.f;
  for (int b = w; b < 64; b += 4){
    int row = step * 64 + b;
    int t = y[(step + 1) * 64 + b];
    if (t != 0){
      const float* a = tlf + (size_t)row * 512 + lane * 8;
      const float* wr = Wop + (size_t)t * 512 + lane * 8;
      float d = 0.f;
      #pragma unroll
      for (int j = 0; j < 8; ++j) d += a[j] * wr[j];
      d = wsum(d);
      if (lane == 0) part += d + bop[t] - __logf(sumexp[row]);
    }
  }
  if (lane == 0) accw[w] = part;
  __syncthreads();
  if (threadIdx.x == 0) atomicAdd(loss, -(accw[0] + accw[1] + accw[2] + accw[3]));
}

__global__ void k_final(const float* __restrict__ loss, float* __restrict__ out){
  if (threadIdx.x == 0 && blockIdx.x == 0) out[0] = loss[0];
}

// ---------------- host launch ----------------

extern "C" void kernel_launch(void* const* d_in, const int* in_sizes, int n_in,
                              void* d_out, int out_size, void* d_ws, size_t ws_size,
                              hipStream_t stream) {
  const float* ctx       = (const float*)d_in[0];
  const float* ctx_mask  = (const float*)d_in[1];
  const float* txt_ctx   = (const float*)d_in[2];
  const int*   y         = (const int*)d_in[3];
  const float* emb       = (const float*)d_in[4];
  const float* W_ctx2ctx = (const float*)d_in[5];
  const float* W_hid2ctx = (const float*)d_in[6];
  const float* w_mlp     = (const float*)d_in[7];
  const float* W_ctx2hid = (const float*)d_in[8];
  const float* W_dec_init= (const float*)d_in[9];
  const float* W_ih0     = (const float*)d_in[10];
  const float* W_hh0     = (const float*)d_in[11];
  const float* b_ih0     = (const float*)d_in[12];
  const float* b_hh0     = (const float*)d_in[13];
  const float* W_ih1     = (const float*)d_in[14];
  const float* W_hh1     = (const float*)d_in[15];
  const float* b_ih1     = (const float*)d_in[16];
  const float* b_hh1     = (const float*)d_in[17];
  const float* W_hid2out = (const float*)d_in[18];
  const float* b_hid2out = (const float*)d_in[19];
  const float* W_out2prob= (const float*)d_in[20];
  const float* b_out2prob= (const float*)d_in[21];
  float* out = (float*)d_out;

  char* p = (char*)d_ws;
  auto alloc = [&](size_t n){ char* r = p; p += (n + 255) & ~(size_t)255; return r; };
  short* Wb_hh0     = (short*)alloc((size_t)1536 * 512 * 2);
  short* Wb_hid2ctx = (short*)alloc((size_t)512 * 512 * 2);
  short* Wb_hh1     = (short*)alloc((size_t)1536 * 512 * 2);
  short* Wb_hid2out = (short*)alloc((size_t)512 * 512 * 2);
  short* Wb_dec     = (short*)alloc((size_t)512 * 512 * 2);
  short* Wb_c2c     = (short*)alloc((size_t)512 * 512 * 2);
  short* Wb_ih0     = (short*)alloc((size_t)1536 * 512 * 2);
  short* Wb_o2p     = (short*)alloc((size_t)32000 * 512 * 2);
  short* WctT       = (short*)alloc((size_t)512 * 512 * 2);
  short* Wb_comb    = (short*)alloc((size_t)1536 * 512 * 2);
  short* ctx_projbf = (short*)alloc((size_t)4096 * 512 * 2);
  float* gi0_all    = (float*)alloc((size_t)3072 * 1536 * 4);
  float* mixed      = (float*)alloc((size_t)64 * 512 * 4);
  float* h0buf      = (float*)alloc((size_t)64 * 512 * 4);
  unsigned short* h_bf    = (unsigned short*)alloc((size_t)64 * 512 * 2);
  unsigned short* h1_bf   = (unsigned short*)alloc((size_t)64 * 512 * 2);
  unsigned short* catt_bf = (unsigned short*)alloc((size_t)64 * 512 * 2);
  float* qpart      = (float*)alloc((size_t)8 * 64 * 512 * 4);
  float* h2_all     = (float*)alloc((size_t)3072 * 512 * 4);
  short* tl_bf      = (short*)alloc((size_t)3072 * 512 * 2);
  float* tl_f       = (float*)alloc((size_t)3072 * 512 * 4);
  // zero region: sumexp(3072) + loss(1) + 3 barrier arrays (64*SLOT each)
  int nbar = 3 * 64 * SLOT;
  float* zreg       = (float*)alloc((size_t)(3073 + nbar) * 4);
  float* sumexp     = zreg;
  float* lossbuf    = zreg + 3072;
  u32* barA         = (u32*)(zreg + 3073);
  u32* barC         = barA + 64 * SLOT;
  u32* barD         = barC + 64 * SLOT;

  dim3 blk(256);
  // ---- phase 0 ----
  CvtJobs jb;
  const float* srcs[8] = {W_hh0, W_hid2ctx, W_hh1, W_hid2out, W_dec_init, W_ctx2ctx, W_ih0, W_out2prob};
  short* dsts[8] = {Wb_hh0, Wb_hid2ctx, Wb_hh1, Wb_hid2out, Wb_dec, Wb_c2c, Wb_ih0, Wb_o2p};
  int sizes4[8] = {1536*512/4, 512*512/4, 1536*512/4, 512*512/4, 512*512/4, 512*512/4, 1536*512/4, 32000*512/4};
  int cum = 0;
  for (int i = 0; i < 8; ++i){ jb.src[i] = srcs[i]; jb.dst[i] = dsts[i]; jb.cum4[i] = cum; cum += sizes4[i]; }
  jb.cum4[8] = cum;
  k_cvt_multi<<<dim3((cum + 255) / 256), blk, 0, stream>>>(jb, cum);
  k_tc<<<dim3(1024), blk, 0, stream>>>(W_ctx2hid, WctT);
  k_gemm_bt_obf<<<dim3(768), blk, 0, stream>>>(W_ih1, WctT, Wb_comb, 512);       // W_comb 1536x512
  k_meanmix<<<dim3(128), blk, 0, stream>>>(ctx, ctx_mask, txt_ctx, mixed);
  k_gemm_bt<<<dim3(32), blk, 0, stream>>>(mixed, Wb_dec, h0buf, 512, 1);         // h0 = tanh(.)
  k_pack_h0<<<dim3(64), blk, 0, stream>>>(h0buf, (u32*)h_bf);
  k_gemm_bt_obf<<<dim3(2048), blk, 0, stream>>>(ctx, Wb_c2c, ctx_projbf, 512);   // ctx_proj bf16
  k_gi0<<<dim3(4608), blk, 0, stream>>>(y, emb, Wb_ih0, b_ih0, gi0_all);
  k_zero<<<dim3((3073 + nbar + 255) / 256), blk, 0, stream>>>(zreg, 3073 + nbar);

  // ---- phase 1: persistent kernel, neighbor-only scattered-slot waits ----
  RB rb;
  rb.gi0 = gi0_all;
  rb.Whh0 = Wb_hh0; rb.bhh0 = b_hh0;
  rb.Whid2ctx = Wb_hid2ctx;
  rb.Whh1 = Wb_hh1; rb.bhh1 = b_hh1;
  rb.Wcomb = Wb_comb; rb.bih1 = b_ih1;
  rb.ctx_proj = ctx_projbf; rb.ctx = ctx; rb.mask = ctx_mask; rb.wmlp = w_mlp;
  rb.h_bf = h_bf; rb.h1_bf = h1_bf; rb.catt_bf = catt_bf;
  rb.qpart = qpart; rb.h2 = h2_all;
  rb.barA = barA; rb.barC = barC; rb.barD = barD;
  void* kargs[] = { &rb };
  hipLaunchCooperativeKernel((const void*)k_recur, dim3(96), blk, kargs, 0, stream);

  // ---- phase 2 ----
  k_logit<<<dim3(1536), blk, 0, stream>>>(h2_all, Wb_hid2out, b_hid2out, tl_bf, tl_f);
  k_sumexp<<<dim3(6000), blk, 0, stream>>>(tl_bf, Wb_o2p, b_out2prob, sumexp);
  k_loss<<<dim3(48), blk, 0, stream>>>(tl_f, W_out2prob, b_out2prob, y, sumexp, lossbuf);
  k_final<<<dim3(1), blk, 0, stream>>>(lossbuf, out);
}